// Round 1
// baseline (2881.053 us; speedup 1.0000x reference)
//
#include <hip/hip_runtime.h>

// ---------------------------------------------------------------------------
// DummyTeModel: 6 chained NT GEMMs (dense w1,w2 then 2x grouped(g1,g2), G=4).
// Strategy: fp32 -> bf16 convert, m97-style MFMA GEMM (128x128 tile, BK=32,
// global_load_lds width=16, 16x16x32 bf16 MFMA, 4 waves x (4x4) frags).
// Threshold is bf16-tolerant (2% of max|ref|).
// ---------------------------------------------------------------------------

typedef __bf16 bf16_t;
typedef __bf16 bf16x8 __attribute__((ext_vector_type(8)));
typedef float f32x4 __attribute__((ext_vector_type(4)));

#define BM 128
#define BN 128
#define BK 32

__device__ __forceinline__ void async_copy16(const bf16_t* g, bf16_t* l) {
    __builtin_amdgcn_global_load_lds(
        (const __attribute__((address_space(1))) void*)g,
        (__attribute__((address_space(3))) void*)l,
        16, 0, 0);
}

// C[g][m][n] = sum_k A[g][m][k] * B[g][n][k] + bias[g][n]
// Grid: (N/BN, M/BM, G). Block: 256 threads = 4 waves, each wave does 64x64.
template <typename OutT>
__global__ __launch_bounds__(256) void gemm_bt_kernel(
    const bf16_t* __restrict__ A,    // [G, M, K] row-major per group
    const bf16_t* __restrict__ B,    // [G, N, K] row-major per group
    const float*  __restrict__ bias, // [G, N] fp32
    OutT* __restrict__ C,            // [G, M, N]
    int M, int N, int K,
    long long sA, long long sB, long long sBias, long long sC)
{
    __shared__ __align__(16) bf16_t lds_a[BM * BK]; // 8 KB, [row][k] unpadded
    __shared__ __align__(16) bf16_t lds_b[BN * BK]; // 8 KB

    const int tid  = threadIdx.x;
    const int lane = tid & 63;
    const int wave = tid >> 6;
    const int wm   = wave >> 1; // 0..1
    const int wn   = wave & 1;  // 0..1

    const int z = blockIdx.z;
    const bf16_t* Ab = A + z * sA + (long long)blockIdx.y * BM * K;
    const bf16_t* Bb = B + z * sB + (long long)blockIdx.x * BN * K;
    const float* biasb = bias + z * sBias + (long long)blockIdx.x * BN;

    // staging: 8 chunks of 1KB per tile; wave w stages chunks {w, w+4}.
    // chunk cc = rows [cc*16, cc*16+16), lane l -> row cc*16 + l/4, k (l&3)*8
    const int srow = lane >> 2;       // 0..15
    const int scol = (lane & 3) * 8;  // 0,8,16,24

    // LDS fragment read offsets (elements); 16B-aligned -> ds_read_b128
    const int l15 = lane & 15;
    const int q   = lane >> 4;        // 0..3
    const int aoff = (wm * 64 + l15) * BK + q * 8;
    const int boff = (wn * 64 + l15) * BK + q * 8;

    f32x4 acc[4][4] = {};

    for (int k0 = 0; k0 < K; k0 += BK) {
#pragma unroll
        for (int t = 0; t < 2; ++t) {
            const int cc = wave + 4 * t; // 0..7
            const int grow = cc * 16 + srow;
            async_copy16(Ab + grow * K + (k0 + scol), lds_a + cc * 512);
            async_copy16(Bb + grow * K + (k0 + scol), lds_b + cc * 512);
        }
        __syncthreads(); // drains vmcnt -> LDS tiles complete

        bf16x8 af[4], bfr[4];
#pragma unroll
        for (int i = 0; i < 4; ++i)
            af[i] = *(const bf16x8*)(lds_a + aoff + i * (16 * BK));
#pragma unroll
        for (int j = 0; j < 4; ++j)
            bfr[j] = *(const bf16x8*)(lds_b + boff + j * (16 * BK));

#pragma unroll
        for (int i = 0; i < 4; ++i)
#pragma unroll
            for (int j = 0; j < 4; ++j)
                acc[i][j] = __builtin_amdgcn_mfma_f32_16x16x32_bf16(
                    af[i], bfr[j], acc[i][j], 0, 0, 0);

        __syncthreads();
    }

    // Epilogue. C/D layout: col = lane&15, row = (lane>>4)*4 + reg  [m89/m91]
    const int row_base = blockIdx.y * BM + wm * 64 + q * 4;
    const int col_base = blockIdx.x * BN + wn * 64 + l15;
    const long long cz = z * sC;
#pragma unroll
    for (int i = 0; i < 4; ++i) {
#pragma unroll
        for (int j = 0; j < 4; ++j) {
            const int col  = col_base + j * 16;
            const int row0 = row_base + i * 16;
            const float bb = biasb[wn * 64 + j * 16 + l15];
            OutT* Cp = C + cz + (long long)row0 * N + col;
#pragma unroll
            for (int r = 0; r < 4; ++r)
                Cp[(long long)r * N] = (OutT)(acc[i][j][r] + bb);
        }
    }
}

// fp32 -> bf16, 8 elements/thread (all sizes divisible by 2048)
__global__ __launch_bounds__(256) void f2bf_kernel(
    const float* __restrict__ in, bf16_t* __restrict__ out, int n8)
{
    int i = blockIdx.x * 256 + threadIdx.x;
    if (i >= n8) return;
    const float4* p = (const float4*)in + 2 * (long long)i;
    float4 a = p[0];
    float4 b = p[1];
    bf16x8 o;
    o[0] = (bf16_t)a.x; o[1] = (bf16_t)a.y; o[2] = (bf16_t)a.z; o[3] = (bf16_t)a.w;
    o[4] = (bf16_t)b.x; o[5] = (bf16_t)b.y; o[6] = (bf16_t)b.z; o[7] = (bf16_t)b.w;
    *((bf16x8*)out + i) = o;
}

static inline void f2bf(const float* in, bf16_t* out, long long n, hipStream_t s) {
    int n8 = (int)(n / 8);
    f2bf_kernel<<<dim3((n8 + 255) / 256), dim3(256), 0, s>>>(in, out, n8);
}

extern "C" void kernel_launch(void* const* d_in, const int* in_sizes, int n_in,
                              void* d_out, int out_size, void* d_ws, size_t ws_size,
                              hipStream_t stream) {
    // Problem constants
    const int H = 2048, I = 4096, T = 16384, G = 4;

    const float* x  = (const float*)d_in[0];  // [T, H]
    const float* w1 = (const float*)d_in[1];  // [2H, H]
    const float* b1 = (const float*)d_in[2];
    const float* w2 = (const float*)d_in[3];  // [H, 2H]
    const float* b2 = (const float*)d_in[4];
    const float* g1w[2] = {(const float*)d_in[5], (const float*)d_in[9]};
    const float* g1b[2] = {(const float*)d_in[6], (const float*)d_in[10]};
    const float* g2w[2] = {(const float*)d_in[7], (const float*)d_in[11]};
    const float* g2b[2] = {(const float*)d_in[8], (const float*)d_in[12]};
    float* out = (float*)d_out;

    // Workspace: XA (T x I bf16 = 134 MB) | XB (134 MB) | WB (67 MB) = 336 MB
    char* ws = (char*)d_ws;
    bf16_t* XA = (bf16_t*)ws;
    bf16_t* XB = (bf16_t*)(ws + 134217728LL);
    bf16_t* WB = (bf16_t*)(ws + 268435456LL);

    // x -> bf16
    f2bf(x, XA, (long long)T * H, stream);

    // dense 1: [T,H] @ [I,H]^T -> XB [T, I]
    f2bf(w1, WB, (long long)I * H, stream);
    gemm_bt_kernel<bf16_t><<<dim3(I / BN, T / BM, 1), dim3(256), 0, stream>>>(
        XA, WB, b1, XB, T, I, H, 0, 0, 0, 0);

    // dense 2: [T,I] @ [H,I]^T -> XA [T, H]
    f2bf(w2, WB, (long long)H * I, stream);
    gemm_bt_kernel<bf16_t><<<dim3(H / BN, T / BM, 1), dim3(256), 0, stream>>>(
        XB, WB, b2, XA, T, H, I, 0, 0, 0, 0);

    const long long Mg = T / G; // 4096 rows per group
    for (int li = 0; li < 2; ++li) {
        // g1: per group [4096,H] @ [I,H]^T -> XB
        f2bf(g1w[li], WB, (long long)G * I * H, stream);
        gemm_bt_kernel<bf16_t><<<dim3(I / BN, (int)(Mg / BM), G), dim3(256), 0, stream>>>(
            XA, WB, g1b[li], XB, (int)Mg, I, H,
            Mg * H, (long long)I * H, I, Mg * I);

        // g2: per group [4096,I] @ [H,I]^T -> XA (or d_out fp32 on last stage)
        f2bf(g2w[li], WB, (long long)G * H * I, stream);
        if (li == 0) {
            gemm_bt_kernel<bf16_t><<<dim3(H / BN, (int)(Mg / BM), G), dim3(256), 0, stream>>>(
                XB, WB, g2b[li], XA, (int)Mg, H, I,
                Mg * I, (long long)H * I, H, Mg * H);
        } else {
            gemm_bt_kernel<float><<<dim3(H / BN, (int)(Mg / BM), G), dim3(256), 0, stream>>>(
                XB, WB, g2b[li], out, (int)Mg, H, I,
                Mg * I, (long long)H * I, H, Mg * H);
        }
    }
}